// Round 19
// baseline (66.653 us; speedup 1.0000x reference)
//
#include <hip/hip_runtime.h>
#include <hip/hip_bf16.h>
#include <math.h>

#define G_   20
#define BT   16

typedef __attribute__((ext_vector_type(8))) short bf8;   // 8 bf16
typedef __attribute__((ext_vector_type(4))) float f4;    // MFMA acc

// ws fragment-group bases (units of one 64-lane x 8-elem fragment group = 512 ushorts)
#define FMB  0
#define FAT  10
#define FUE2 12
#define FGE1 20
#define FGE2 32
#define FPR  56
#define FTOT 62

__device__ __forceinline__ unsigned cvt2(float x, float y){
    float2 f; f.x = x; f.y = y;
    __hip_bfloat162 h = __float22bfloat162_rn(f);     // v_cvt_pk_bf16_f32
    return *reinterpret_cast<unsigned*>(&h);
}
__device__ __forceinline__ unsigned short cvt1(float x){
    __hip_bfloat16 h = __float2bfloat16(x);
    return *reinterpret_cast<unsigned short*>(&h);
}
__device__ __forceinline__ bf8 pack8(float4 a, float4 b){
    union { bf8 v; unsigned u[4]; } t;
    t.u[0] = cvt2(a.x, a.y); t.u[1] = cvt2(a.z, a.w);
    t.u[2] = cvt2(b.x, b.y); t.u[3] = cvt2(b.z, b.w);
    return t.v;
}

// ---------------- prep: weights -> fragment-linear bf16 in ws ----------------
__global__ __launch_bounds__(256) void vargr_prep(
    const float* __restrict__ ue_w1, const float* __restrict__ ue_w2,
    const float* __restrict__ ge_w1, const float* __restrict__ ge_w2,
    const float* __restrict__ at_w1, const float* __restrict__ pr_w1,
    unsigned short* __restrict__ ws)
{
    int f = blockIdx.x * 256 + threadIdx.x;
    if (f >= FTOT * 64) return;
    int lane = f & 63, grp = f >> 6;
    int col = lane & 15;
    int q8  = (lane >> 4) * 8;
    float v[8];
    if (grp < FAT){
        int g = grp - FMB; int nt = g >> 1; int k0 = (g & 1)*32 + q8; int c = nt*16 + col;
        #pragma unroll
        for (int q = 0; q < 8; ++q)
            v[q] = (c < 64) ? ue_w1[(k0+q)*64 + c] : at_w1[(k0+q)*16 + (c - 64)];
    } else if (grp < FUE2){
        int g = grp - FAT; int k0 = g*32 + q8;
        #pragma unroll
        for (int q = 0; q < 8; ++q) v[q] = at_w1[(64 + k0 + q)*16 + col];
    } else if (grp < FGE1){
        int g = grp - FUE2; int nt = g >> 1; int k0 = (g & 1)*32 + q8;
        #pragma unroll
        for (int q = 0; q < 8; ++q) v[q] = ue_w2[(k0+q)*64 + nt*16 + col];
    } else if (grp < FGE2){
        int g = grp - FGE1; int nt = g >> 1; int k0 = (g & 1)*32 + q8;
        #pragma unroll
        for (int q = 0; q < 8; ++q) v[q] = ge_w1[(k0+q)*96 + nt*16 + col];
    } else if (grp < FPR){
        int g = grp - FGE2; int nt = g / 3; int k0 = (g % 3)*32 + q8;
        #pragma unroll
        for (int q = 0; q < 8; ++q) v[q] = ge_w2[(k0+q)*128 + nt*16 + col];
    } else {
        int g = grp - FPR; int k0 = g*32 + q8;
        #pragma unroll
        for (int q = 0; q < 8; ++q) v[q] = (col < 8) ? pr_w1[(k0+q)*8 + col] : 0.f;
    }
    union { bf8 b; unsigned u[4]; } t;
    t.u[0] = cvt2(v[0], v[1]); t.u[1] = cvt2(v[2], v[3]);
    t.u[2] = cvt2(v[4], v[5]); t.u[3] = cvt2(v[6], v[7]);
    *reinterpret_cast<bf8*>(ws + (size_t)f * 8) = t.b;
}

// ---------------- main: 1024 threads = 16 waves, ONE batch per wave ----------------
__global__ __launch_bounds__(1024, 4) void vargr_main(
    const int*   __restrict__ group_inputs,
    const int*   __restrict__ item_inputs,
    const int*   __restrict__ group_members,
    const float* __restrict__ eps,
    const float* __restrict__ user_emb,
    const float* __restrict__ item_emb,
    const float* __restrict__ ue_b1, const float* __restrict__ ue_b2,
    const float* __restrict__ ge_b1, const float* __restrict__ ge_b2,
    const float* __restrict__ at_b1, const float* __restrict__ at_w2,
    const float* __restrict__ at_b2, const float* __restrict__ pr_b1,
    const float* __restrict__ pr_w2, const float* __restrict__ pr_b2,
    const unsigned short* __restrict__ ws,
    float* __restrict__ out)
{
    // LDS: 4352+1280+1280+4352+4096+4352+8448 = 28160 B
    __shared__ float ieb[BT*68];
    __shared__ float wsm[BT*G_];
    __shared__ int   sidx[BT*G_];
    __shared__ unsigned short xAh[BT*136];
    __shared__ float gefb[BT*64];
    __shared__ unsigned short xBh[BT*136];
    __shared__ float x3u[BT*132];            // later aliased as ncf bf16 [16][200]

    const int tid = threadIdx.x;
    const int w = tid >> 6, l = tid & 63;    // wave w owns batch bb = w
    const int lq = l >> 4, lr = l & 15;
    const int bbase = blockIdx.x * BT;
    const int bb = w;
    const bf8* wsf = (const bf8*)ws;

    bf8 bfr[5][2];
    #pragma unroll
    for (int nt = 0; nt < 5; ++nt)
        #pragma unroll
        for (int kt = 0; kt < 2; ++kt)
            bfr[nt][kt] = wsf[(FMB + nt*2 + kt)*64 + l];
    bf8 abot0 = wsf[(FAT + 0)*64 + l];
    bf8 abot1 = wsf[(FAT + 1)*64 + l];

    float bias1[4];
    #pragma unroll
    for (int nt = 0; nt < 4; ++nt) bias1[nt] = ue_b1[nt*16 + lr];
    const float aw2  = at_w2[lr];
    const float atb2 = at_b2[0];
    const float atb1 = at_b1[lr];

    // ---- stage own ieb row + own sidx (wave-local) ----
    {
        int item = item_inputs[bbase + bb];
        if (l < 16)
            ((float4*)(ieb + bb*68))[l] = ((const float4*)(item_emb + (size_t)item*64))[l];
        int gid = group_inputs[bbase + bb];
        if (l < G_) sidx[bb*G_ + l] = group_members[gid*G_ + l];
    }

    // ---- issue ALL 20 member-row gathers NOW (single latency epoch, pre-barrier) ----
    bf8 a0, a1, b0, b1;
    {
        int sxm = sidx[bb*G_ + lr];                                  // main tile: member lr
        const float4* pm = (const float4*)(user_emb + (size_t)sxm*64) + lq*2;
        float4 m0 = pm[0], m1 = pm[1], m2 = pm[8], m3 = pm[9];
        int rr2 = (lr < 4) ? lr : 3;                                 // rem tile: member 16+lr (clamped dup)
        int sxr = sidx[bb*G_ + 16 + rr2];
        const float4* pr_ = (const float4*)(user_emb + (size_t)sxr*64) + lq*2;
        float4 q0 = pr_[0], q1 = pr_[1], q2 = pr_[8], q3 = pr_[9];
        a0 = pack8(m0, m1); a1 = pack8(m2, m3);
        b0 = pack8(q0, q1); b1 = pack8(q2, q3);
    }

    __syncthreads();    // publish ieb for the tv GEMM

    // ---- tv GEMM (redundant per wave, M=16 all block batches): extract own row ----
    float tvi;
    {
        f4 tvacc = (f4){0.f, 0.f, 0.f, 0.f};
        #pragma unroll
        for (int kt = 0; kt < 2; ++kt){
            const float* ap = ieb + lr*68 + kt*32 + lq*8;
            bf8 a = pack8(*(const float4*)ap, *(const float4*)(ap + 4));
            tvacc = __builtin_amdgcn_mfma_f32_16x16x32_bf16(a, kt ? abot1 : abot0, tvacc, 0, 0, 0);
        }
        int wm = w & 3;
        float src = (wm == 0) ? tvacc[0] : (wm == 1) ? tvacc[1] : (wm == 2) ? tvacc[2] : tvacc[3];
        tvi = __shfl(src, (w >> 2)*16 + lr) + atb1;
    }

    // ---- member GEMMs: main tile (members 0-15) + remainder tile (16-19, rows 0-3 valid) ----
    f4 accM[5], accR[5];
    #pragma unroll
    for (int nt = 0; nt < 5; ++nt){ accM[nt] = (f4){0.f,0.f,0.f,0.f}; accR[nt] = (f4){0.f,0.f,0.f,0.f}; }
    #pragma unroll
    for (int nt = 0; nt < 5; ++nt){
        accM[nt] = __builtin_amdgcn_mfma_f32_16x16x32_bf16(a0, bfr[nt][0], accM[nt], 0, 0, 0);
        accM[nt] = __builtin_amdgcn_mfma_f32_16x16x32_bf16(a1, bfr[nt][1], accM[nt], 0, 0, 0);
        accR[nt] = __builtin_amdgcn_mfma_f32_16x16x32_bf16(b0, bfr[nt][0], accR[nt], 0, 0, 0);
        accR[nt] = __builtin_amdgcn_mfma_f32_16x16x32_bf16(b1, bfr[nt][1], accR[nt], 0, 0, 0);
    }

    // ---- mean of relu-hidden over 20 members -> xAh row bb ----
    #pragma unroll
    for (int nt = 0; nt < 4; ++nt){
        float rs = 0.f;
        #pragma unroll
        for (int rr = 0; rr < 4; ++rr) rs += fmaxf(accM[nt][rr] + bias1[nt], 0.f);
        if (lq == 0){   // remainder C-rows 0-3 live in quarter 0
            #pragma unroll
            for (int rr = 0; rr < 4; ++rr) rs += fmaxf(accR[nt][rr] + bias1[nt], 0.f);
        }
        rs += __shfl_xor(rs, 16);
        rs += __shfl_xor(rs, 32);
        if (lq == nt) xAh[bb*136 + nt*16 + lr] = cvt1(rs * (1.f / G_));
    }
    // ---- attention scores ----
    {
        float vv[4];
        #pragma unroll
        for (int rr = 0; rr < 4; ++rr) vv[rr] = fmaxf(accM[4][rr] + tvi, 0.f) * aw2;
        #pragma unroll
        for (int rr = 0; rr < 4; ++rr){
            vv[rr] += __shfl_xor(vv[rr], 1, 16);
            vv[rr] += __shfl_xor(vv[rr], 2, 16);
            vv[rr] += __shfl_xor(vv[rr], 4, 16);
            vv[rr] += __shfl_xor(vv[rr], 8, 16);
        }
        if (lr == 0){
            #pragma unroll
            for (int rr = 0; rr < 4; ++rr) wsm[bb*G_ + 4*lq + rr] = vv[rr] + atb2;
        }
        float vr[4];
        #pragma unroll
        for (int rr = 0; rr < 4; ++rr) vr[rr] = fmaxf(accR[4][rr] + tvi, 0.f) * aw2;
        #pragma unroll
        for (int rr = 0; rr < 4; ++rr){
            vr[rr] += __shfl_xor(vr[rr], 1, 16);
            vr[rr] += __shfl_xor(vr[rr], 2, 16);
            vr[rr] += __shfl_xor(vr[rr], 4, 16);
            vr[rr] += __shfl_xor(vr[rr], 8, 16);
        }
        if (lq == 0 && lr == 0){
            #pragma unroll
            for (int rr = 0; rr < 4; ++rr) wsm[bb*G_ + 16 + rr] = vr[rr] + atb2;
        }
    }
    // ---- softmax over 20 scores (wave-local) ----
    {
        float sval = (l < G_) ? wsm[bb*G_ + l] : -3.0e38f;
        float mx = sval;
        mx = fmaxf(mx, __shfl_xor(mx, 1, 32));
        mx = fmaxf(mx, __shfl_xor(mx, 2, 32));
        mx = fmaxf(mx, __shfl_xor(mx, 4, 32));
        mx = fmaxf(mx, __shfl_xor(mx, 8, 32));
        mx = fmaxf(mx, __shfl_xor(mx, 16, 32));
        float e = (l < G_) ? expf(sval - mx) : 0.f;
        float sm = e;
        sm += __shfl_xor(sm, 1, 32);
        sm += __shfl_xor(sm, 2, 32);
        sm += __shfl_xor(sm, 4, 32);
        sm += __shfl_xor(sm, 8, 32);
        sm += __shfl_xor(sm, 16, 32);
        if (l < G_) wsm[bb*G_ + l] = e / sm;
    }
    // ---- attention-weighted member sum (rows L1/L2-warm from own gather) ----
    {
        float ga = 0.f;
        #pragma unroll
        for (int g = 0; g < G_; ++g)
            ga += wsm[bb*G_ + g] * user_emb[(size_t)sidx[bb*G_ + g]*64 + l];
        gefb[bb*64 + l] = ga;
    }

    // ---- eps prefetch for the tail wave (overlaps barrier wait) ----
    float ev[16];
    if (w == 0){
        #pragma unroll
        for (int j = 0; j < 16; ++j)
            ev[j] = eps[(size_t)(bbase + j)*64 + l];
    }

    // ---- single barrier: publish xAh, gefb, ieb. Waves 1-15 retire. ----
    __syncthreads();
    if (w != 0) return;

    // ---- L1: gz0 = relu(hbar @ ue_w2 + b2), 64 cols (wave-local, no barriers) ----
    #pragma unroll
    for (int nt = 0; nt < 4; ++nt){
        int col = nt*16 + lr;
        f4 acc = (f4){0.f, 0.f, 0.f, 0.f};
        #pragma unroll
        for (int kt = 0; kt < 2; ++kt){
            bf8 a = *(const bf8*)(xAh + lr*136 + kt*32 + lq*8);
            acc = __builtin_amdgcn_mfma_f32_16x16x32_bf16(a, wsf[(FUE2 + nt*2 + kt)*64 + l], acc, 0, 0, 0);
        }
        float bs = ue_b2[col];
        #pragma unroll
        for (int rr = 0; rr < 4; ++rr)
            xBh[(4*lq + rr)*136 + col] = cvt1(fmaxf(acc[rr] + bs, 0.f));
    }
    // ---- L2: t1 = relu(gz0 @ ge_w1 + b1), 96 cols ----
    #pragma unroll
    for (int t = 0; t < 6; ++t){
        int col = t*16 + lr;
        f4 acc = (f4){0.f, 0.f, 0.f, 0.f};
        #pragma unroll
        for (int kt = 0; kt < 2; ++kt){
            bf8 a = *(const bf8*)(xBh + lr*136 + kt*32 + lq*8);
            acc = __builtin_amdgcn_mfma_f32_16x16x32_bf16(a, wsf[(FGE1 + t*2 + kt)*64 + l], acc, 0, 0, 0);
        }
        float bs = ge_b1[col];
        #pragma unroll
        for (int rr = 0; rr < 4; ++rr)
            xAh[(4*lq + rr)*136 + col] = cvt1(fmaxf(acc[rr] + bs, 0.f));
    }
    // ---- L3: x3 = t1 @ ge_w2 + b2, 128 cols (raw f32) ----
    #pragma unroll
    for (int t = 0; t < 8; ++t){
        int col = t*16 + lr;
        f4 acc = (f4){0.f, 0.f, 0.f, 0.f};
        #pragma unroll
        for (int kt = 0; kt < 3; ++kt){
            bf8 a = *(const bf8*)(xAh + lr*136 + kt*32 + lq*8);
            acc = __builtin_amdgcn_mfma_f32_16x16x32_bf16(a, wsf[(FGE2 + t*3 + kt)*64 + l], acc, 0, 0, 0);
        }
        float bs = ge_b2[col];
        #pragma unroll
        for (int rr = 0; rr < 4; ++rr)
            x3u[(4*lq + rr)*132 + col] = acc[rr] + bs;
    }

    // ---- phase 3: reparameterize (x3u reads into regs first) ----
    float gefv[BT];
    #pragma unroll
    for (int j = 0; j < BT; ++j){
        float mu  = x3u[j*132 + l];
        float sgr = x3u[j*132 + 64 + l];
        float sg  = 0.1f + 0.9f / (1.f + expf(-sgr));
        gefv[j] = gefb[j*64 + l] + mu + sg * ev[j];
    }
    asm volatile("" ::: "memory");          // order x3u reads before ncf alias writes
    unsigned short* ncf = (unsigned short*)x3u;   // [16][200] bf16, overlays x3u
    #pragma unroll
    for (int j = 0; j < BT; ++j){
        float g  = gefv[j];
        float ie = ieb[j*68 + l];
        ncf[j*200 + l]       = cvt1(g * ie);
        ncf[j*200 + 64 + l]  = cvt1(g);
        ncf[j*200 + 128 + l] = cvt1(ie);
    }
    // ---- predictor ----
    {
        f4 acc = (f4){0.f, 0.f, 0.f, 0.f};
        #pragma unroll
        for (int kt = 0; kt < 6; ++kt){
            bf8 a = *(const bf8*)(ncf + lr*200 + kt*32 + lq*8);
            acc = __builtin_amdgcn_mfma_f32_16x16x32_bf16(a, wsf[(FPR + kt)*64 + l], acc, 0, 0, 0);
        }
        float pb1 = (lr < 8) ? pr_b1[lr] : 0.f;
        float pw2 = (lr < 8) ? pr_w2[lr] : 0.f;
        float pb2 = pr_b2[0];
        float vv[4];
        #pragma unroll
        for (int rr = 0; rr < 4; ++rr) vv[rr] = fmaxf(acc[rr] + pb1, 0.f) * pw2;
        #pragma unroll
        for (int rr = 0; rr < 4; ++rr){
            vv[rr] += __shfl_xor(vv[rr], 1, 16);
            vv[rr] += __shfl_xor(vv[rr], 2, 16);
            vv[rr] += __shfl_xor(vv[rr], 4, 16);
            vv[rr] += __shfl_xor(vv[rr], 8, 16);
        }
        if (lr == 0){
            #pragma unroll
            for (int rr = 0; rr < 4; ++rr)
                out[bbase + 4*lq + rr] = 1.f / (1.f + expf(-(vv[rr] + pb2)));
        }
    }
}

extern "C" void kernel_launch(void* const* d_in, const int* in_sizes, int n_in,
                              void* d_out, int out_size, void* d_ws, size_t ws_size,
                              hipStream_t stream) {
    const int*   group_inputs  = (const int*)d_in[0];
    const int*   item_inputs   = (const int*)d_in[1];
    const int*   group_members = (const int*)d_in[2];
    const float* eps           = (const float*)d_in[3];
    const float* user_emb      = (const float*)d_in[4];
    const float* item_emb      = (const float*)d_in[5];
    const float* ue_w1 = (const float*)d_in[6];
    const float* ue_b1 = (const float*)d_in[7];
    const float* ue_w2 = (const float*)d_in[8];
    const float* ue_b2 = (const float*)d_in[9];
    const float* ge_w1 = (const float*)d_in[10];
    const float* ge_b1 = (const float*)d_in[11];
    const float* ge_w2 = (const float*)d_in[12];
    const float* ge_b2 = (const float*)d_in[13];
    const float* at_w1 = (const float*)d_in[14];
    const float* at_b1 = (const float*)d_in[15];
    const float* at_w2 = (const float*)d_in[16];
    const float* at_b2 = (const float*)d_in[17];
    const float* pr_w1 = (const float*)d_in[18];
    const float* pr_b1 = (const float*)d_in[19];
    const float* pr_w2 = (const float*)d_in[20];
    const float* pr_b2 = (const float*)d_in[21];
    float* out = (float*)d_out;
    unsigned short* ws = (unsigned short*)d_ws;

    vargr_prep<<<(FTOT*64 + 255)/256, 256, 0, stream>>>(
        ue_w1, ue_w2, ge_w1, ge_w2, at_w1, pr_w1, ws);

    const int nb = in_sizes[0];          // B = 16384, divisible by BT=16
    vargr_main<<<nb / BT, 1024, 0, stream>>>(
        group_inputs, item_inputs, group_members, eps, user_emb, item_emb,
        ue_b1, ue_b2, ge_b1, ge_b2, at_b1, at_w2, at_b2, pr_b1, pr_w2, pr_b2,
        ws, out);
}

// Round 20
// 41.336 us; speedup vs baseline: 1.6125x; 1.6125x over previous
//
#include <hip/hip_runtime.h>
#include <hip/hip_bf16.h>
#include <math.h>

#define G_   20
#define BT   16

typedef __attribute__((ext_vector_type(8))) short bf8;   // 8 bf16
typedef __attribute__((ext_vector_type(4))) float f4;    // MFMA acc

// ws fragment-group bases (units of one 64-lane x 8-elem fragment group = 512 ushorts)
#define FMB  0
#define FAT  10
#define FUE2 12
#define FGE1 20
#define FGE2 32
#define FPR  56
#define FTOT 62

__device__ __forceinline__ unsigned cvt2(float x, float y){
    float2 f; f.x = x; f.y = y;
    __hip_bfloat162 h = __float22bfloat162_rn(f);     // v_cvt_pk_bf16_f32
    return *reinterpret_cast<unsigned*>(&h);
}
__device__ __forceinline__ unsigned short cvt1(float x){
    __hip_bfloat16 h = __float2bfloat16(x);
    return *reinterpret_cast<unsigned short*>(&h);
}
__device__ __forceinline__ bf8 pack8(float4 a, float4 b){
    union { bf8 v; unsigned u[4]; } t;
    t.u[0] = cvt2(a.x, a.y); t.u[1] = cvt2(a.z, a.w);
    t.u[2] = cvt2(b.x, b.y); t.u[3] = cvt2(b.z, b.w);
    return t.v;
}

// ---------------- prep: weights -> fragment-linear bf16 in ws ----------------
__global__ __launch_bounds__(256) void vargr_prep(
    const float* __restrict__ ue_w1, const float* __restrict__ ue_w2,
    const float* __restrict__ ge_w1, const float* __restrict__ ge_w2,
    const float* __restrict__ at_w1, const float* __restrict__ pr_w1,
    unsigned short* __restrict__ ws)
{
    int f = blockIdx.x * 256 + threadIdx.x;
    if (f >= FTOT * 64) return;
    int lane = f & 63, grp = f >> 6;
    int col = lane & 15;
    int q8  = (lane >> 4) * 8;
    float v[8];
    if (grp < FAT){
        int g = grp - FMB; int nt = g >> 1; int k0 = (g & 1)*32 + q8; int c = nt*16 + col;
        #pragma unroll
        for (int q = 0; q < 8; ++q)
            v[q] = (c < 64) ? ue_w1[(k0+q)*64 + c] : at_w1[(k0+q)*16 + (c - 64)];
    } else if (grp < FUE2){
        int g = grp - FAT; int k0 = g*32 + q8;
        #pragma unroll
        for (int q = 0; q < 8; ++q) v[q] = at_w1[(64 + k0 + q)*16 + col];
    } else if (grp < FGE1){
        int g = grp - FUE2; int nt = g >> 1; int k0 = (g & 1)*32 + q8;
        #pragma unroll
        for (int q = 0; q < 8; ++q) v[q] = ue_w2[(k0+q)*64 + nt*16 + col];
    } else if (grp < FGE2){
        int g = grp - FGE1; int nt = g >> 1; int k0 = (g & 1)*32 + q8;
        #pragma unroll
        for (int q = 0; q < 8; ++q) v[q] = ge_w1[(k0+q)*96 + nt*16 + col];
    } else if (grp < FPR){
        int g = grp - FGE2; int nt = g / 3; int k0 = (g % 3)*32 + q8;
        #pragma unroll
        for (int q = 0; q < 8; ++q) v[q] = ge_w2[(k0+q)*128 + nt*16 + col];
    } else {
        int g = grp - FPR; int k0 = g*32 + q8;
        #pragma unroll
        for (int q = 0; q < 8; ++q) v[q] = (col < 8) ? pr_w1[(k0+q)*8 + col] : 0.f;
    }
    union { bf8 b; unsigned u[4]; } t;
    t.u[0] = cvt2(v[0], v[1]); t.u[1] = cvt2(v[2], v[3]);
    t.u[2] = cvt2(v[4], v[5]); t.u[3] = cvt2(v[6], v[7]);
    *reinterpret_cast<bf8*>(ws + (size_t)f * 8) = t.b;
}

// ---------------- main ----------------
__global__ __launch_bounds__(256, 3) void vargr_main(
    const int*   __restrict__ group_inputs,
    const int*   __restrict__ item_inputs,
    const int*   __restrict__ group_members,
    const float* __restrict__ eps,
    const float* __restrict__ user_emb,
    const float* __restrict__ item_emb,
    const float* __restrict__ ue_b1, const float* __restrict__ ue_b2,
    const float* __restrict__ ge_b1, const float* __restrict__ ge_b2,
    const float* __restrict__ at_b1, const float* __restrict__ at_w2,
    const float* __restrict__ at_b2, const float* __restrict__ pr_b1,
    const float* __restrict__ pr_w2, const float* __restrict__ pr_b2,
    const unsigned short* __restrict__ ws,
    float* __restrict__ out)
{
    __shared__ unsigned short xAh[BT*136];
    __shared__ unsigned short xBh[BT*136];
    __shared__ float ieb[BT*68];
    __shared__ float gefb[BT*64];
    __shared__ float wsm[BT*G_];
    __shared__ int   sidx[BT*G_];
    __shared__ float x3u[BT*132];            // L3 raw f32; later aliased as ncf bf16 [16][200]

    const int tid = threadIdx.x;
    const int w = tid >> 6, l = tid & 63;
    const int lq = l >> 4, lr = l & 15;
    const int bbase = blockIdx.x * BT;
    const bf8* wsf = (const bf8*)ws;

    bf8 bfr[5][2];
    #pragma unroll
    for (int nt = 0; nt < 5; ++nt)
        #pragma unroll
        for (int kt = 0; kt < 2; ++kt)
            bfr[nt][kt] = wsf[(FMB + nt*2 + kt)*64 + l];
    bf8 abot0 = wsf[(FAT + 0)*64 + l];
    bf8 abot1 = wsf[(FAT + 1)*64 + l];

    float bias1[4];
    #pragma unroll
    for (int nt = 0; nt < 4; ++nt) bias1[nt] = ue_b1[nt*16 + lr];
    const float aw2  = at_w2[lr];
    const float atb2 = at_b2[0];

    {
        int bb = 4*w + lq;
        int item = item_inputs[bbase + bb];
        ((float4*)(ieb + bb*68))[lr] = ((const float4*)(item_emb + (size_t)item*64))[lr];
    }
    if (l < G_){
        #pragma unroll
        for (int i = 0; i < 4; ++i){
            int bb = 4*w + i;
            int gid = group_inputs[bbase + bb];
            sidx[bb*G_ + l] = group_members[gid*G_ + l];
        }
    }
    __syncthreads();

    // ---- issue remainder + batch-0 gathers NOW (latency hides under tv GEMM) ----
    float4 r0, r1, r2, r3;
    {
        int sx = sidx[(4*w + (lr >> 2))*G_ + 16 + (lr & 3)];
        const float4* p = (const float4*)(user_emb + (size_t)sx*64) + lq*2;
        r0 = p[0]; r1 = p[1]; r2 = p[8]; r3 = p[9];
    }
    float4 c0, c1, c2, c3;
    {
        int sx = sidx[(4*w + 0)*G_ + lr];
        const float4* p = (const float4*)(user_emb + (size_t)sx*64) + lq*2;
        c0 = p[0]; c1 = p[1]; c2 = p[8]; c3 = p[9];
    }

    // ---- tv GEMM: tv[b][u] = ie[b] . at_w1[64:,u], M=16 ----
    f4 tvacc = (f4){0.f, 0.f, 0.f, 0.f};
    #pragma unroll
    for (int kt = 0; kt < 2; ++kt){
        const float* ap = ieb + lr*68 + kt*32 + lq*8;
        bf8 a = pack8(*(const float4*)ap, *(const float4*)(ap + 4));
        tvacc = __builtin_amdgcn_mfma_f32_16x16x32_bf16(a, kt ? abot1 : abot0, tvacc, 0, 0, 0);
    }
    const float atb1 = at_b1[lr];
    float tvi[4];
    #pragma unroll
    for (int i = 0; i < 4; ++i)
        tvi[i] = __shfl(tvacc[i], w*16 + lr) + atb1;

    // ---- remainder tile: members 16..19 of this wave's 4 batches ----
    float rem[4];
    {
        bf8 a0 = pack8(r0, r1);
        bf8 a1 = pack8(r2, r3);
        f4 acc[5];
        #pragma unroll
        for (int nt = 0; nt < 5; ++nt) acc[nt] = (f4){0.f, 0.f, 0.f, 0.f};
        #pragma unroll
        for (int nt = 0; nt < 5; ++nt){
            acc[nt] = __builtin_amdgcn_mfma_f32_16x16x32_bf16(a0, bfr[nt][0], acc[nt], 0, 0, 0);
            acc[nt] = __builtin_amdgcn_mfma_f32_16x16x32_bf16(a1, bfr[nt][1], acc[nt], 0, 0, 0);
        }
        #pragma unroll
        for (int nt = 0; nt < 4; ++nt){
            float rs = 0.f;
            #pragma unroll
            for (int rr = 0; rr < 4; ++rr) rs += fmaxf(acc[nt][rr] + bias1[nt], 0.f);
            rem[nt] = rs;
        }
        float tvq = (lq == 0) ? tvi[0] : (lq == 1) ? tvi[1] : (lq == 2) ? tvi[2] : tvi[3];
        float vv[4];
        #pragma unroll
        for (int rr = 0; rr < 4; ++rr) vv[rr] = fmaxf(acc[4][rr] + tvq, 0.f) * aw2;
        #pragma unroll
        for (int rr = 0; rr < 4; ++rr){
            vv[rr] += __shfl_xor(vv[rr], 1, 16);
            vv[rr] += __shfl_xor(vv[rr], 2, 16);
            vv[rr] += __shfl_xor(vv[rr], 4, 16);
            vv[rr] += __shfl_xor(vv[rr], 8, 16);
        }
        if (lr == 0){
            #pragma unroll
            for (int rr = 0; rr < 4; ++rr)
                wsm[(4*w + lq)*G_ + 16 + rr] = vv[rr] + atb2;
        }
    }

    // ---- main pipeline: batch i computes while batch i+1's gather is in flight ----
    #pragma unroll
    for (int i = 0; i < 4; ++i){
        float4 n0, n1, n2, n3;
        if (i < 3){
            int sx = sidx[(4*w + i + 1)*G_ + lr];
            const float4* p = (const float4*)(user_emb + (size_t)sx*64) + lq*2;
            n0 = p[0]; n1 = p[1]; n2 = p[8]; n3 = p[9];
        }
        const int bb = 4*w + i;
        bf8 a0 = pack8(c0, c1);
        bf8 a1 = pack8(c2, c3);
        f4 acc[5];
        #pragma unroll
        for (int nt = 0; nt < 5; ++nt) acc[nt] = (f4){0.f, 0.f, 0.f, 0.f};
        #pragma unroll
        for (int nt = 0; nt < 5; ++nt){
            acc[nt] = __builtin_amdgcn_mfma_f32_16x16x32_bf16(a0, bfr[nt][0], acc[nt], 0, 0, 0);
            acc[nt] = __builtin_amdgcn_mfma_f32_16x16x32_bf16(a1, bfr[nt][1], acc[nt], 0, 0, 0);
        }
        #pragma unroll
        for (int nt = 0; nt < 4; ++nt){
            float rs = 0.f;
            #pragma unroll
            for (int rr = 0; rr < 4; ++rr) rs += fmaxf(acc[nt][rr] + bias1[nt], 0.f);
            if (lq == i) rs += rem[nt];
            rs += __shfl_xor(rs, 16);
            rs += __shfl_xor(rs, 32);
            if (lq == nt) xAh[bb*136 + nt*16 + lr] = cvt1(rs * (1.f / G_));
        }
        {
            float vv[4];
            #pragma unroll
            for (int rr = 0; rr < 4; ++rr) vv[rr] = fmaxf(acc[4][rr] + tvi[i], 0.f) * aw2;
            #pragma unroll
            for (int rr = 0; rr < 4; ++rr){
                vv[rr] += __shfl_xor(vv[rr], 1, 16);
                vv[rr] += __shfl_xor(vv[rr], 2, 16);
                vv[rr] += __shfl_xor(vv[rr], 4, 16);
                vv[rr] += __shfl_xor(vv[rr], 8, 16);
            }
            if (lr == 0){
                #pragma unroll
                for (int rr = 0; rr < 4; ++rr)
                    wsm[bb*G_ + 4*lq + rr] = vv[rr] + atb2;
            }
        }
        {
            float sval = (l < G_) ? wsm[bb*G_ + l] : -3.0e38f;
            float mx = sval;
            mx = fmaxf(mx, __shfl_xor(mx, 1, 32));
            mx = fmaxf(mx, __shfl_xor(mx, 2, 32));
            mx = fmaxf(mx, __shfl_xor(mx, 4, 32));
            mx = fmaxf(mx, __shfl_xor(mx, 8, 32));
            mx = fmaxf(mx, __shfl_xor(mx, 16, 32));
            float e = (l < G_) ? expf(sval - mx) : 0.f;
            float sm = e;
            sm += __shfl_xor(sm, 1, 32);
            sm += __shfl_xor(sm, 2, 32);
            sm += __shfl_xor(sm, 4, 32);
            sm += __shfl_xor(sm, 8, 32);
            sm += __shfl_xor(sm, 16, 32);
            if (l < G_) wsm[bb*G_ + l] = e / sm;
        }
        {
            float ga = 0.f;
            #pragma unroll
            for (int g = 0; g < G_; ++g)
                ga += wsm[bb*G_ + g] * user_emb[(size_t)sidx[bb*G_ + g]*64 + l];
            gefb[bb*64 + l] = ga;
        }
        c0 = n0; c1 = n1; c2 = n2; c3 = n3;
    }

    // ---- single barrier: publish xAh, gefb, ieb. Waves 1-3 retire. ----
    __syncthreads();
    if (w != 0) return;

    // ---- eps prefetch for all 16 batches (completes under the MFMA chain) ----
    float ev[16];
    #pragma unroll
    for (int bb = 0; bb < BT; ++bb)
        ev[bb] = eps[(size_t)(bbase + bb)*64 + l];

    // ---- L1: gz0 = relu(hbar @ ue_w2 + b2), 64 cols (wave-local, no barriers) ----
    #pragma unroll
    for (int nt = 0; nt < 4; ++nt){
        int col = nt*16 + lr;
        f4 acc = (f4){0.f, 0.f, 0.f, 0.f};
        #pragma unroll
        for (int kt = 0; kt < 2; ++kt){
            bf8 a = *(const bf8*)(xAh + lr*136 + kt*32 + lq*8);
            acc = __builtin_amdgcn_mfma_f32_16x16x32_bf16(a, wsf[(FUE2 + nt*2 + kt)*64 + l], acc, 0, 0, 0);
        }
        float bs = ue_b2[col];
        #pragma unroll
        for (int rr = 0; rr < 4; ++rr)
            xBh[(4*lq + rr)*136 + col] = cvt1(fmaxf(acc[rr] + bs, 0.f));
    }
    // ---- L2: t1 = relu(gz0 @ ge_w1 + b1), 96 cols ----
    #pragma unroll
    for (int t = 0; t < 6; ++t){
        int col = t*16 + lr;
        f4 acc = (f4){0.f, 0.f, 0.f, 0.f};
        #pragma unroll
        for (int kt = 0; kt < 2; ++kt){
            bf8 a = *(const bf8*)(xBh + lr*136 + kt*32 + lq*8);
            acc = __builtin_amdgcn_mfma_f32_16x16x32_bf16(a, wsf[(FGE1 + t*2 + kt)*64 + l], acc, 0, 0, 0);
        }
        float bs = ge_b1[col];
        #pragma unroll
        for (int rr = 0; rr < 4; ++rr)
            xAh[(4*lq + rr)*136 + col] = cvt1(fmaxf(acc[rr] + bs, 0.f));
    }
    // ---- L3: x3 = t1 @ ge_w2 + b2, 128 cols (raw f32) ----
    #pragma unroll
    for (int t = 0; t < 8; ++t){
        int col = t*16 + lr;
        f4 acc = (f4){0.f, 0.f, 0.f, 0.f};
        #pragma unroll
        for (int kt = 0; kt < 3; ++kt){
            bf8 a = *(const bf8*)(xAh + lr*136 + kt*32 + lq*8);
            acc = __builtin_amdgcn_mfma_f32_16x16x32_bf16(a, wsf[(FGE2 + t*3 + kt)*64 + l], acc, 0, 0, 0);
        }
        float bs = ge_b2[col];
        #pragma unroll
        for (int rr = 0; rr < 4; ++rr)
            x3u[(4*lq + rr)*132 + col] = acc[rr] + bs;
    }

    // ---- phase 3: reparameterize (all x3u reads into regs first) ----
    float gefv[BT];
    #pragma unroll
    for (int bb = 0; bb < BT; ++bb){
        float mu  = x3u[bb*132 + l];
        float sgr = x3u[bb*132 + 64 + l];
        float sg  = 0.1f + 0.9f / (1.f + expf(-sgr));
        gefv[bb] = gefb[bb*64 + l] + mu + sg * ev[bb];
    }
    asm volatile("" ::: "memory");          // order x3u reads before ncf alias writes
    unsigned short* ncf = (unsigned short*)x3u;   // [16][200] bf16, overlays x3u
    #pragma unroll
    for (int bb = 0; bb < BT; ++bb){
        float gef = gefv[bb];
        float iev = ieb[bb*68 + l];
        ncf[bb*200 + l]       = cvt1(gef * iev);
        ncf[bb*200 + 64 + l]  = cvt1(gef);
        ncf[bb*200 + 128 + l] = cvt1(iev);
    }
    // ---- predictor ----
    {
        f4 acc = (f4){0.f, 0.f, 0.f, 0.f};
        #pragma unroll
        for (int kt = 0; kt < 6; ++kt){
            bf8 a = *(const bf8*)(ncf + lr*200 + kt*32 + lq*8);
            acc = __builtin_amdgcn_mfma_f32_16x16x32_bf16(a, wsf[(FPR + kt)*64 + l], acc, 0, 0, 0);
        }
        float pb1 = (lr < 8) ? pr_b1[lr] : 0.f;
        float pw2 = (lr < 8) ? pr_w2[lr] : 0.f;
        float pb2 = pr_b2[0];
        float vv[4];
        #pragma unroll
        for (int rr = 0; rr < 4; ++rr) vv[rr] = fmaxf(acc[rr] + pb1, 0.f) * pw2;
        #pragma unroll
        for (int rr = 0; rr < 4; ++rr){
            vv[rr] += __shfl_xor(vv[rr], 1, 16);
            vv[rr] += __shfl_xor(vv[rr], 2, 16);
            vv[rr] += __shfl_xor(vv[rr], 4, 16);
            vv[rr] += __shfl_xor(vv[rr], 8, 16);
        }
        if (lr == 0){
            #pragma unroll
            for (int rr = 0; rr < 4; ++rr)
                out[bbase + 4*lq + rr] = 1.f / (1.f + expf(-(vv[rr] + pb2)));
        }
    }
}

extern "C" void kernel_launch(void* const* d_in, const int* in_sizes, int n_in,
                              void* d_out, int out_size, void* d_ws, size_t ws_size,
                              hipStream_t stream) {
    const int*   group_inputs  = (const int*)d_in[0];
    const int*   item_inputs   = (const int*)d_in[1];
    const int*   group_members = (const int*)d_in[2];
    const float* eps           = (const float*)d_in[3];
    const float* user_emb      = (const float*)d_in[4];
    const float* item_emb      = (const float*)d_in[5];
    const float* ue_w1 = (const float*)d_in[6];
    const float* ue_b1 = (const float*)d_in[7];
    const float* ue_w2 = (const float*)d_in[8];
    const float* ue_b2 = (const float*)d_in[9];
    const float* ge_w1 = (const float*)d_in[10];
    const float* ge_b1 = (const float*)d_in[11];
    const float* ge_w2 = (const float*)d_in[12];
    const float* ge_b2 = (const float*)d_in[13];
    const float* at_w1 = (const float*)d_in[14];
    const float* at_b1 = (const float*)d_in[15];
    const float* at_w2 = (const float*)d_in[16];
    const float* at_b2 = (const float*)d_in[17];
    const float* pr_w1 = (const float*)d_in[18];
    const float* pr_b1 = (const float*)d_in[19];
    const float* pr_w2 = (const float*)d_in[20];
    const float* pr_b2 = (const float*)d_in[21];
    float* out = (float*)d_out;
    unsigned short* ws = (unsigned short*)d_ws;

    vargr_prep<<<(FTOT*64 + 255)/256, 256, 0, stream>>>(
        ue_w1, ue_w2, ge_w1, ge_w2, at_w1, pr_w1, ws);

    const int nb = in_sizes[0];          // B = 16384, divisible by BT=16
    vargr_main<<<nb / BT, 256, 0, stream>>>(
        group_inputs, item_inputs, group_members, eps, user_emb, item_emb,
        ue_b1, ue_b2, ge_b1, ge_b2, at_b1, at_w2, at_b2, pr_b1, pr_w2, pr_b2,
        ws, out);
}

// Round 21
// 39.957 us; speedup vs baseline: 1.6681x; 1.0345x over previous
//
#include <hip/hip_runtime.h>
#include <hip/hip_bf16.h>
#include <math.h>

#define G_   20
#define BT   16

typedef __attribute__((ext_vector_type(8))) short bf8;   // 8 bf16
typedef __attribute__((ext_vector_type(4))) float f4;    // MFMA acc

// ws fragment-group bases (units of one 64-lane x 8-elem fragment group = 512 ushorts)
#define FMB  0
#define FAT  10
#define FUE2 12
#define FGE1 20
#define FGE2 32
#define FPR  56
#define FTOT 62

__device__ __forceinline__ unsigned cvt2(float x, float y){
    float2 f; f.x = x; f.y = y;
    __hip_bfloat162 h = __float22bfloat162_rn(f);     // v_cvt_pk_bf16_f32
    return *reinterpret_cast<unsigned*>(&h);
}
__device__ __forceinline__ unsigned short cvt1(float x){
    __hip_bfloat16 h = __float2bfloat16(x);
    return *reinterpret_cast<unsigned short*>(&h);
}
__device__ __forceinline__ bf8 pack8(float4 a, float4 b){
    union { bf8 v; unsigned u[4]; } t;
    t.u[0] = cvt2(a.x, a.y); t.u[1] = cvt2(a.z, a.w);
    t.u[2] = cvt2(b.x, b.y); t.u[3] = cvt2(b.z, b.w);
    return t.v;
}

// ---------------- prep: weights -> fragment-linear bf16 in ws ----------------
__global__ __launch_bounds__(256) void vargr_prep(
    const float* __restrict__ ue_w1, const float* __restrict__ ue_w2,
    const float* __restrict__ ge_w1, const float* __restrict__ ge_w2,
    const float* __restrict__ at_w1, const float* __restrict__ pr_w1,
    unsigned short* __restrict__ ws)
{
    int f = blockIdx.x * 256 + threadIdx.x;
    if (f >= FTOT * 64) return;
    int lane = f & 63, grp = f >> 6;
    int col = lane & 15;
    int q8  = (lane >> 4) * 8;
    float v[8];
    if (grp < FAT){
        int g = grp - FMB; int nt = g >> 1; int k0 = (g & 1)*32 + q8; int c = nt*16 + col;
        #pragma unroll
        for (int q = 0; q < 8; ++q)
            v[q] = (c < 64) ? ue_w1[(k0+q)*64 + c] : at_w1[(k0+q)*16 + (c - 64)];
    } else if (grp < FUE2){
        int g = grp - FAT; int k0 = g*32 + q8;
        #pragma unroll
        for (int q = 0; q < 8; ++q) v[q] = at_w1[(64 + k0 + q)*16 + col];
    } else if (grp < FGE1){
        int g = grp - FUE2; int nt = g >> 1; int k0 = (g & 1)*32 + q8;
        #pragma unroll
        for (int q = 0; q < 8; ++q) v[q] = ue_w2[(k0+q)*64 + nt*16 + col];
    } else if (grp < FGE2){
        int g = grp - FGE1; int nt = g >> 1; int k0 = (g & 1)*32 + q8;
        #pragma unroll
        for (int q = 0; q < 8; ++q) v[q] = ge_w1[(k0+q)*96 + nt*16 + col];
    } else if (grp < FPR){
        int g = grp - FGE2; int nt = g / 3; int k0 = (g % 3)*32 + q8;
        #pragma unroll
        for (int q = 0; q < 8; ++q) v[q] = ge_w2[(k0+q)*128 + nt*16 + col];
    } else {
        int g = grp - FPR; int k0 = g*32 + q8;
        #pragma unroll
        for (int q = 0; q < 8; ++q) v[q] = (col < 8) ? pr_w1[(k0+q)*8 + col] : 0.f;
    }
    union { bf8 b; unsigned u[4]; } t;
    t.u[0] = cvt2(v[0], v[1]); t.u[1] = cvt2(v[2], v[3]);
    t.u[2] = cvt2(v[4], v[5]); t.u[3] = cvt2(v[6], v[7]);
    *reinterpret_cast<bf8*>(ws + (size_t)f * 8) = t.b;
}

// ---------------- main ----------------
__global__ __launch_bounds__(256, 2) void vargr_main(
    const int*   __restrict__ group_inputs,
    const int*   __restrict__ item_inputs,
    const int*   __restrict__ group_members,
    const float* __restrict__ eps,
    const float* __restrict__ user_emb,
    const float* __restrict__ item_emb,
    const float* __restrict__ ue_b1, const float* __restrict__ ue_b2,
    const float* __restrict__ ge_b1, const float* __restrict__ ge_b2,
    const float* __restrict__ at_b1, const float* __restrict__ at_w2,
    const float* __restrict__ at_b2, const float* __restrict__ pr_b1,
    const float* __restrict__ pr_w2, const float* __restrict__ pr_b2,
    const unsigned short* __restrict__ ws,
    float* __restrict__ out)
{
    __shared__ unsigned short xAh[BT*136];
    __shared__ unsigned short xBh[BT*136];
    __shared__ float ieb[BT*68];
    __shared__ float gefb[BT*64];
    __shared__ float wsm[BT*G_];
    __shared__ int   sidx[BT*G_];
    __shared__ float x3u[BT*132];            // L3 raw f32; later aliased as ncf bf16 [16][200]

    const int tid = threadIdx.x;
    const int w = tid >> 6, l = tid & 63;
    const int lq = l >> 4, lr = l & 15;
    const int bbase = blockIdx.x * BT;
    const bf8* wsf = (const bf8*)ws;

    bf8 bfr[5][2];
    #pragma unroll
    for (int nt = 0; nt < 5; ++nt)
        #pragma unroll
        for (int kt = 0; kt < 2; ++kt)
            bfr[nt][kt] = wsf[(FMB + nt*2 + kt)*64 + l];
    bf8 abot0 = wsf[(FAT + 0)*64 + l];
    bf8 abot1 = wsf[(FAT + 1)*64 + l];

    float bias1[4];
    #pragma unroll
    for (int nt = 0; nt < 4; ++nt) bias1[nt] = ue_b1[nt*16 + lr];
    const float aw2  = at_w2[lr];
    const float atb2 = at_b2[0];

    {
        int bb = 4*w + lq;
        int item = item_inputs[bbase + bb];
        ((float4*)(ieb + bb*68))[lr] = ((const float4*)(item_emb + (size_t)item*64))[lr];
    }
    if (l < G_){
        #pragma unroll
        for (int i = 0; i < 4; ++i){
            int bb = 4*w + i;
            int gid = group_inputs[bbase + bb];
            sidx[bb*G_ + l] = group_members[gid*G_ + l];
        }
    }
    __syncthreads();

    // ---- issue remainder + batch-0 gathers NOW (latency hides under tv GEMM) ----
    float4 r0, r1, r2, r3;
    {
        int sx = sidx[(4*w + (lr >> 2))*G_ + 16 + (lr & 3)];
        const float4* p = (const float4*)(user_emb + (size_t)sx*64) + lq*2;
        r0 = p[0]; r1 = p[1]; r2 = p[8]; r3 = p[9];
    }
    float4 c0, c1, c2, c3;
    {
        int sx = sidx[(4*w + 0)*G_ + lr];
        const float4* p = (const float4*)(user_emb + (size_t)sx*64) + lq*2;
        c0 = p[0]; c1 = p[1]; c2 = p[8]; c3 = p[9];
    }

    // ---- tv GEMM: tv[b][u] = ie[b] . at_w1[64:,u], M=16 ----
    f4 tvacc = (f4){0.f, 0.f, 0.f, 0.f};
    #pragma unroll
    for (int kt = 0; kt < 2; ++kt){
        const float* ap = ieb + lr*68 + kt*32 + lq*8;
        bf8 a = pack8(*(const float4*)ap, *(const float4*)(ap + 4));
        tvacc = __builtin_amdgcn_mfma_f32_16x16x32_bf16(a, kt ? abot1 : abot0, tvacc, 0, 0, 0);
    }
    const float atb1 = at_b1[lr];
    float tvi[4];
    #pragma unroll
    for (int i = 0; i < 4; ++i)
        tvi[i] = __shfl(tvacc[i], w*16 + lr) + atb1;

    // ---- remainder tile: members 16..19 of this wave's 4 batches ----
    float rem[4];
    {
        bf8 a0 = pack8(r0, r1);
        bf8 a1 = pack8(r2, r3);
        f4 acc[5];
        #pragma unroll
        for (int nt = 0; nt < 5; ++nt) acc[nt] = (f4){0.f, 0.f, 0.f, 0.f};
        #pragma unroll
        for (int nt = 0; nt < 5; ++nt){
            acc[nt] = __builtin_amdgcn_mfma_f32_16x16x32_bf16(a0, bfr[nt][0], acc[nt], 0, 0, 0);
            acc[nt] = __builtin_amdgcn_mfma_f32_16x16x32_bf16(a1, bfr[nt][1], acc[nt], 0, 0, 0);
        }
        #pragma unroll
        for (int nt = 0; nt < 4; ++nt){
            float rs = 0.f;
            #pragma unroll
            for (int rr = 0; rr < 4; ++rr) rs += fmaxf(acc[nt][rr] + bias1[nt], 0.f);
            rem[nt] = rs;
        }
        float tvq = (lq == 0) ? tvi[0] : (lq == 1) ? tvi[1] : (lq == 2) ? tvi[2] : tvi[3];
        float vv[4];
        #pragma unroll
        for (int rr = 0; rr < 4; ++rr) vv[rr] = fmaxf(acc[4][rr] + tvq, 0.f) * aw2;
        #pragma unroll
        for (int rr = 0; rr < 4; ++rr){
            vv[rr] += __shfl_xor(vv[rr], 1, 16);
            vv[rr] += __shfl_xor(vv[rr], 2, 16);
            vv[rr] += __shfl_xor(vv[rr], 4, 16);
            vv[rr] += __shfl_xor(vv[rr], 8, 16);
        }
        if (lr == 0){
            #pragma unroll
            for (int rr = 0; rr < 4; ++rr)
                wsm[(4*w + lq)*G_ + 16 + rr] = vv[rr] + atb2;
        }
    }

    // ---- main pipeline: batch i computes while batch i+1's gather is in flight ----
    #pragma unroll
    for (int i = 0; i < 4; ++i){
        float4 n0, n1, n2, n3;
        if (i < 3){
            int sx = sidx[(4*w + i + 1)*G_ + lr];
            const float4* p = (const float4*)(user_emb + (size_t)sx*64) + lq*2;
            n0 = p[0]; n1 = p[1]; n2 = p[8]; n3 = p[9];
        }
        const int bb = 4*w + i;
        bf8 a0 = pack8(c0, c1);
        bf8 a1 = pack8(c2, c3);
        f4 acc[5];
        #pragma unroll
        for (int nt = 0; nt < 5; ++nt) acc[nt] = (f4){0.f, 0.f, 0.f, 0.f};
        #pragma unroll
        for (int nt = 0; nt < 5; ++nt){
            acc[nt] = __builtin_amdgcn_mfma_f32_16x16x32_bf16(a0, bfr[nt][0], acc[nt], 0, 0, 0);
            acc[nt] = __builtin_amdgcn_mfma_f32_16x16x32_bf16(a1, bfr[nt][1], acc[nt], 0, 0, 0);
        }
        #pragma unroll
        for (int nt = 0; nt < 4; ++nt){
            float rs = 0.f;
            #pragma unroll
            for (int rr = 0; rr < 4; ++rr) rs += fmaxf(acc[nt][rr] + bias1[nt], 0.f);
            if (lq == i) rs += rem[nt];
            rs += __shfl_xor(rs, 16);
            rs += __shfl_xor(rs, 32);
            if (lq == nt) xAh[bb*136 + nt*16 + lr] = cvt1(rs * (1.f / G_));
        }
        {
            float vv[4];
            #pragma unroll
            for (int rr = 0; rr < 4; ++rr) vv[rr] = fmaxf(acc[4][rr] + tvi[i], 0.f) * aw2;
            #pragma unroll
            for (int rr = 0; rr < 4; ++rr){
                vv[rr] += __shfl_xor(vv[rr], 1, 16);
                vv[rr] += __shfl_xor(vv[rr], 2, 16);
                vv[rr] += __shfl_xor(vv[rr], 4, 16);
                vv[rr] += __shfl_xor(vv[rr], 8, 16);
            }
            if (lr == 0){
                #pragma unroll
                for (int rr = 0; rr < 4; ++rr)
                    wsm[bb*G_ + 4*lq + rr] = vv[rr] + atb2;
            }
        }
        {
            float sval = (l < G_) ? wsm[bb*G_ + l] : -3.0e38f;
            float mx = sval;
            mx = fmaxf(mx, __shfl_xor(mx, 1, 32));
            mx = fmaxf(mx, __shfl_xor(mx, 2, 32));
            mx = fmaxf(mx, __shfl_xor(mx, 4, 32));
            mx = fmaxf(mx, __shfl_xor(mx, 8, 32));
            mx = fmaxf(mx, __shfl_xor(mx, 16, 32));
            float e = (l < G_) ? expf(sval - mx) : 0.f;
            float sm = e;
            sm += __shfl_xor(sm, 1, 32);
            sm += __shfl_xor(sm, 2, 32);
            sm += __shfl_xor(sm, 4, 32);
            sm += __shfl_xor(sm, 8, 32);
            sm += __shfl_xor(sm, 16, 32);
            if (l < G_) wsm[bb*G_ + l] = e / sm;
        }
        {
            float ga = 0.f;
            #pragma unroll
            for (int g = 0; g < G_; ++g)
                ga += wsm[bb*G_ + g] * user_emb[(size_t)sidx[bb*G_ + g]*64 + l];
            gefb[bb*64 + l] = ga;
        }
        c0 = n0; c1 = n1; c2 = n2; c3 = n3;
    }

    // ---- single barrier: publish xAh, gefb, ieb. Waves 1-3 retire. ----
    __syncthreads();
    if (w != 0) return;

    // ---- eps prefetch for all 16 batches (completes under the MFMA chain) ----
    float ev[16];
    #pragma unroll
    for (int bb = 0; bb < BT; ++bb)
        ev[bb] = eps[(size_t)(bbase + bb)*64 + l];

    // ---- L1: gz0 = relu(hbar @ ue_w2 + b2), 64 cols (wave-local, no barriers) ----
    #pragma unroll
    for (int nt = 0; nt < 4; ++nt){
        int col = nt*16 + lr;
        f4 acc = (f4){0.f, 0.f, 0.f, 0.f};
        #pragma unroll
        for (int kt = 0; kt < 2; ++kt){
            bf8 a = *(const bf8*)(xAh + lr*136 + kt*32 + lq*8);
            acc = __builtin_amdgcn_mfma_f32_16x16x32_bf16(a, wsf[(FUE2 + nt*2 + kt)*64 + l], acc, 0, 0, 0);
        }
        float bs = ue_b2[col];
        #pragma unroll
        for (int rr = 0; rr < 4; ++rr)
            xBh[(4*lq + rr)*136 + col] = cvt1(fmaxf(acc[rr] + bs, 0.f));
    }
    // ---- L2: t1 = relu(gz0 @ ge_w1 + b1), 96 cols ----
    #pragma unroll
    for (int t = 0; t < 6; ++t){
        int col = t*16 + lr;
        f4 acc = (f4){0.f, 0.f, 0.f, 0.f};
        #pragma unroll
        for (int kt = 0; kt < 2; ++kt){
            bf8 a = *(const bf8*)(xBh + lr*136 + kt*32 + lq*8);
            acc = __builtin_amdgcn_mfma_f32_16x16x32_bf16(a, wsf[(FGE1 + t*2 + kt)*64 + l], acc, 0, 0, 0);
        }
        float bs = ge_b1[col];
        #pragma unroll
        for (int rr = 0; rr < 4; ++rr)
            xAh[(4*lq + rr)*136 + col] = cvt1(fmaxf(acc[rr] + bs, 0.f));
    }
    // ---- L3: x3 = t1 @ ge_w2 + b2, 128 cols (raw f32) ----
    #pragma unroll
    for (int t = 0; t < 8; ++t){
        int col = t*16 + lr;
        f4 acc = (f4){0.f, 0.f, 0.f, 0.f};
        #pragma unroll
        for (int kt = 0; kt < 3; ++kt){
            bf8 a = *(const bf8*)(xAh + lr*136 + kt*32 + lq*8);
            acc = __builtin_amdgcn_mfma_f32_16x16x32_bf16(a, wsf[(FGE2 + t*3 + kt)*64 + l], acc, 0, 0, 0);
        }
        float bs = ge_b2[col];
        #pragma unroll
        for (int rr = 0; rr < 4; ++rr)
            x3u[(4*lq + rr)*132 + col] = acc[rr] + bs;
    }

    // ---- phase 3: reparameterize (all x3u reads into regs first) ----
    float gefv[BT];
    #pragma unroll
    for (int bb = 0; bb < BT; ++bb){
        float mu  = x3u[bb*132 + l];
        float sgr = x3u[bb*132 + 64 + l];
        float sg  = 0.1f + 0.9f / (1.f + expf(-sgr));
        gefv[bb] = gefb[bb*64 + l] + mu + sg * ev[bb];
    }
    asm volatile("" ::: "memory");          // order x3u reads before ncf alias writes
    unsigned short* ncf = (unsigned short*)x3u;   // [16][200] bf16, overlays x3u
    #pragma unroll
    for (int bb = 0; bb < BT; ++bb){
        float gef = gefv[bb];
        float iev = ieb[bb*68 + l];
        ncf[bb*200 + l]       = cvt1(gef * iev);
        ncf[bb*200 + 64 + l]  = cvt1(gef);
        ncf[bb*200 + 128 + l] = cvt1(iev);
    }
    // ---- predictor ----
    {
        f4 acc = (f4){0.f, 0.f, 0.f, 0.f};
        #pragma unroll
        for (int kt = 0; kt < 6; ++kt){
            bf8 a = *(const bf8*)(ncf + lr*200 + kt*32 + lq*8);
            acc = __builtin_amdgcn_mfma_f32_16x16x32_bf16(a, wsf[(FPR + kt)*64 + l], acc, 0, 0, 0);
        }
        float pb1 = (lr < 8) ? pr_b1[lr] : 0.f;
        float pw2 = (lr < 8) ? pr_w2[lr] : 0.f;
        float pb2 = pr_b2[0];
        float vv[4];
        #pragma unroll
        for (int rr = 0; rr < 4; ++rr) vv[rr] = fmaxf(acc[rr] + pb1, 0.f) * pw2;
        #pragma unroll
        for (int rr = 0; rr < 4; ++rr){
            vv[rr] += __shfl_xor(vv[rr], 1, 16);
            vv[rr] += __shfl_xor(vv[rr], 2, 16);
            vv[rr] += __shfl_xor(vv[rr], 4, 16);
            vv[rr] += __shfl_xor(vv[rr], 8, 16);
        }
        if (lr == 0){
            #pragma unroll
            for (int rr = 0; rr < 4; ++rr)
                out[bbase + 4*lq + rr] = 1.f / (1.f + expf(-(vv[rr] + pb2)));
        }
    }
}

extern "C" void kernel_launch(void* const* d_in, const int* in_sizes, int n_in,
                              void* d_out, int out_size, void* d_ws, size_t ws_size,
                              hipStream_t stream) {
    const int*   group_inputs  = (const int*)d_in[0];
    const int*   item_inputs   = (const int*)d_in[1];
    const int*   group_members = (const int*)d_in[2];
    const float* eps           = (const float*)d_in[3];
    const float* user_emb      = (const float*)d_in[4];
    const float* item_emb      = (const float*)d_in[5];
    const float* ue_w1 = (const float*)d_in[6];
    const float* ue_b1 = (const float*)d_in[7];
    const float* ue_w2 = (const float*)d_in[8];
    const float* ue_b2 = (const float*)d_in[9];
    const float* ge_w1 = (const float*)d_in[10];
    const float* ge_b1 = (const float*)d_in[11];
    const float* ge_w2 = (const float*)d_in[12];
    const float* ge_b2 = (const float*)d_in[13];
    const float* at_w1 = (const float*)d_in[14];
    const float* at_b1 = (const float*)d_in[15];
    const float* at_w2 = (const float*)d_in[16];
    const float* at_b2 = (const float*)d_in[17];
    const float* pr_w1 = (const float*)d_in[18];
    const float* pr_b1 = (const float*)d_in[19];
    const float* pr_w2 = (const float*)d_in[20];
    const float* pr_b2 = (const float*)d_in[21];
    float* out = (float*)d_out;
    unsigned short* ws = (unsigned short*)d_ws;

    vargr_prep<<<(FTOT*64 + 255)/256, 256, 0, stream>>>(
        ue_w1, ue_w2, ge_w1, ge_w2, at_w1, pr_w1, ws);

    const int nb = in_sizes[0];          // B = 16384, divisible by BT=16
    vargr_main<<<nb / BT, 256, 0, stream>>>(
        group_inputs, item_inputs, group_members, eps, user_emb, item_emb,
        ue_b1, ue_b2, ge_b1, ge_b2, at_b1, at_w2, at_b2, pr_b1, pr_w2, pr_b2,
        ws, out);
}